// Round 1
// baseline (1415.464 us; speedup 1.0000x reference)
//
#include <hip/hip_runtime.h>

#define NB 32
#define NN 256
#define DD 64

// One block per batch (32 blocks), one thread per node (256 threads).
// h kept in registers; matvecs fully unrolled; reductions staged through a
// 33-float-padded LDS buffer in two 32-wide column passes (2-way bank
// aliasing only, which is free on CDNA4).
__global__ __launch_bounds__(256, 1) void pnet_kernel(
    const float* __restrict__ x,
    const float* __restrict__ W1,  const float* __restrict__ b1,
    const float* __restrict__ g1,  const float* __restrict__ beta1,
    const float* __restrict__ We1, const float* __restrict__ be1,
    const float* __restrict__ ge1, const float* __restrict__ bte1,
    const float* __restrict__ We2, const float* __restrict__ be2,
    const float* __restrict__ ge2, const float* __restrict__ bte2,
    const float* __restrict__ Wg1, const float* __restrict__ bg1,
    const float* __restrict__ Wg2, const float* __restrict__ bg2,
    float* __restrict__ out)
{
    __shared__ float R[NN * 33];     // 33.8 KB staging for column reductions
    __shared__ float pA[8 * 32];     // per-group partial max (or max in pooling)
    __shared__ float pB[8 * 32];     // per-group partial min (or sum in pooling)
    __shared__ float redmax[DD];
    __shared__ float redmin[DD];
    __shared__ float xg[2 * DD];
    __shared__ float hid[DD];

    const int b = blockIdx.x;
    const int t = threadIdx.x;          // node index
    const int dl = t & 31;              // reduction column within 32-wide pass
    const int gg = t >> 5;              // reduction row-group (0..7), 32 rows each

    // ---------------- layer 1: h = bn(relu(x @ W1 + b1)) ----------------
    float4 xv = *(const float4*)(x + ((size_t)b * NN + t) * 4);
    float h[DD];
#pragma unroll
    for (int i = 0; i < 16; ++i) {
        float4 a  = ((const float4*)b1)[i];
        float4 w0 = ((const float4*)W1)[0 * 16 + i];
        float4 w1 = ((const float4*)W1)[1 * 16 + i];
        float4 w2 = ((const float4*)W1)[2 * 16 + i];
        float4 w3 = ((const float4*)W1)[3 * 16 + i];
        a.x += xv.x * w0.x + xv.y * w1.x + xv.z * w2.x + xv.w * w3.x;
        a.y += xv.x * w0.y + xv.y * w1.y + xv.z * w2.y + xv.w * w3.y;
        a.z += xv.x * w0.z + xv.y * w1.z + xv.z * w2.z + xv.w * w3.z;
        a.w += xv.x * w0.w + xv.y * w1.w + xv.z * w2.w + xv.w * w3.w;
        float4 g  = ((const float4*)g1)[i];
        float4 bt = ((const float4*)beta1)[i];
        h[4 * i + 0] = g.x * fmaxf(a.x, 0.f) + bt.x;
        h[4 * i + 1] = g.y * fmaxf(a.y, 0.f) + bt.y;
        h[4 * i + 2] = g.z * fmaxf(a.z, 0.f) + bt.z;
        h[4 * i + 3] = g.w * fmaxf(a.w, 0.f) + bt.w;
    }

    // ---------------- two edge convs ----------------
    const float* Wes[2]  = {We1, We2};
    const float* bes[2]  = {be1, be2};
    const float* ges[2]  = {ge1, ge2};
    const float* btes[2] = {bte1, bte2};

    for (int c = 0; c < 2; ++c) {
        const float* We = Wes[c];
        float4 ti[16], tj[16];
#pragma unroll
        for (int i = 0; i < 16; ++i) {
            ti[i] = make_float4(0.f, 0.f, 0.f, 0.f);
            tj[i] = make_float4(0.f, 0.f, 0.f, 0.f);
        }
        // ti = h @ Wi (rows 0..63), tj = h @ Wj (rows 64..127); weights are
        // wave-uniform reads.
#pragma unroll
        for (int k = 0; k < 64; ++k) {
            float hk = h[k];
            const float4* wi = (const float4*)(We + k * 64);
            const float4* wj = (const float4*)(We + (64 + k) * 64);
#pragma unroll
            for (int i = 0; i < 16; ++i) {
                float4 a  = wi[i];
                float4 bq = wj[i];
                ti[i].x += hk * a.x;  ti[i].y += hk * a.y;
                ti[i].z += hk * a.z;  ti[i].w += hk * a.w;
                tj[i].x += hk * bq.x; tj[i].y += hk * bq.y;
                tj[i].z += hk * bq.z; tj[i].w += hk * bq.w;
            }
        }

        // per-batch max/min of tj over nodes, in two 32-column passes
#pragma unroll
        for (int p = 0; p < 2; ++p) {
            __syncthreads();   // R free from previous use
#pragma unroll
            for (int i = 0; i < 8; ++i) {
                int ii = p * 8 + i;
                R[t * 33 + 4 * i + 0] = tj[ii].x;
                R[t * 33 + 4 * i + 1] = tj[ii].y;
                R[t * 33 + 4 * i + 2] = tj[ii].z;
                R[t * 33 + 4 * i + 3] = tj[ii].w;
            }
            __syncthreads();
            float mx = -3.402823466e+38f, mn = 3.402823466e+38f;
#pragma unroll
            for (int s = 0; s < 32; ++s) {
                float v = R[(gg * 32 + s) * 33 + dl];
                mx = fmaxf(mx, v);
                mn = fminf(mn, v);
            }
            pA[gg * 32 + dl] = mx;
            pB[gg * 32 + dl] = mn;
            __syncthreads();
            if (t < 32) {
                float amax = pA[t], amin = pB[t];
#pragma unroll
                for (int q = 1; q < 8; ++q) {
                    amax = fmaxf(amax, pA[q * 32 + t]);
                    amin = fminf(amin, pB[q * 32 + t]);
                }
                redmax[p * 32 + t] = amax;
                redmin[p * 32 + t] = amin;
            }
        }
        __syncthreads();

        // h_new[d] = ge[d]*relu(ti[d] + pick(tj over m) + be[d]) + bte[d]
        const float4* gev  = (const float4*)ges[c];
        const float4* bev  = (const float4*)bes[c];
        const float4* btev = (const float4*)btes[c];
#pragma unroll
        for (int i = 0; i < 16; ++i) {
            float4 gv  = gev[i];
            float4 be4 = bev[i];
            float4 bt4 = btev[i];
            float s0 = ti[i].x + (gv.x >= 0.f ? redmax[4 * i + 0] : redmin[4 * i + 0]) + be4.x;
            float s1 = ti[i].y + (gv.y >= 0.f ? redmax[4 * i + 1] : redmin[4 * i + 1]) + be4.y;
            float s2 = ti[i].z + (gv.z >= 0.f ? redmax[4 * i + 2] : redmin[4 * i + 2]) + be4.z;
            float s3 = ti[i].w + (gv.w >= 0.f ? redmax[4 * i + 3] : redmin[4 * i + 3]) + be4.w;
            h[4 * i + 0] = gv.x * fmaxf(s0, 0.f) + bt4.x;
            h[4 * i + 1] = gv.y * fmaxf(s1, 0.f) + bt4.y;
            h[4 * i + 2] = gv.z * fmaxf(s2, 0.f) + bt4.z;
            h[4 * i + 3] = gv.w * fmaxf(s3, 0.f) + bt4.w;
        }
    }

    // ---------------- global pooling: mean & max over nodes ----------------
#pragma unroll
    for (int p = 0; p < 2; ++p) {
        __syncthreads();
#pragma unroll
        for (int i = 0; i < 8; ++i) {
            R[t * 33 + 4 * i + 0] = h[p * 32 + 4 * i + 0];
            R[t * 33 + 4 * i + 1] = h[p * 32 + 4 * i + 1];
            R[t * 33 + 4 * i + 2] = h[p * 32 + 4 * i + 2];
            R[t * 33 + 4 * i + 3] = h[p * 32 + 4 * i + 3];
        }
        __syncthreads();
        float mx = -3.402823466e+38f, sm = 0.f;
#pragma unroll
        for (int s = 0; s < 32; ++s) {
            float v = R[(gg * 32 + s) * 33 + dl];
            mx = fmaxf(mx, v);
            sm += v;
        }
        pA[gg * 32 + dl] = mx;
        pB[gg * 32 + dl] = sm;
        __syncthreads();
        if (t < 32) {
            float amax = pA[t], asum = pB[t];
#pragma unroll
            for (int q = 1; q < 8; ++q) {
                amax = fmaxf(amax, pA[q * 32 + t]);
                asum += pB[q * 32 + t];
            }
            xg[p * 32 + t]      = asum * (1.f / 256.f);  // mean half
            xg[64 + p * 32 + t] = amax;                  // max half
        }
    }
    __syncthreads();

    // ---------------- head MLP ----------------
    if (t < 64) {
        float a = bg1[t];
#pragma unroll 8
        for (int k = 0; k < 128; ++k) a += xg[k] * Wg1[k * 64 + t];
        hid[t] = fmaxf(a, 0.f);
    }
    __syncthreads();
    if (t < 2) {
        float o = bg2[t];
#pragma unroll 8
        for (int j = 0; j < 64; ++j) o += hid[j] * Wg2[j * 2 + t];
        out[b * 2 + t] = o;
    }
}

extern "C" void kernel_launch(void* const* d_in, const int* in_sizes, int n_in,
                              void* d_out, int out_size, void* d_ws, size_t ws_size,
                              hipStream_t stream) {
    const float* x     = (const float*)d_in[0];
    const float* W1    = (const float*)d_in[1];
    const float* b1    = (const float*)d_in[2];
    const float* g1    = (const float*)d_in[3];
    const float* beta1 = (const float*)d_in[4];
    const float* We1   = (const float*)d_in[5];
    const float* be1   = (const float*)d_in[6];
    const float* ge1   = (const float*)d_in[7];
    const float* bte1  = (const float*)d_in[8];
    const float* We2   = (const float*)d_in[9];
    const float* be2   = (const float*)d_in[10];
    const float* ge2   = (const float*)d_in[11];
    const float* bte2  = (const float*)d_in[12];
    const float* Wg1   = (const float*)d_in[13];
    const float* bg1   = (const float*)d_in[14];
    const float* Wg2   = (const float*)d_in[15];
    const float* bg2   = (const float*)d_in[16];

    pnet_kernel<<<dim3(NB), dim3(NN), 0, stream>>>(
        x, W1, b1, g1, beta1, We1, be1, ge1, bte1,
        We2, be2, ge2, bte2, Wg1, bg1, Wg2, bg2, (float*)d_out);
}

// Round 2
// 428.147 us; speedup vs baseline: 3.3060x; 3.3060x over previous
//
#include <hip/hip_runtime.h>

#define NB 32
#define NN 256
#define DD 64

// One block per batch (32 blocks), one thread per node (256 threads).
// KEY CHANGE vs R1: the edge-conv matvec is split into two sequential passes
// (tj first, reduce, then ti) so peak live registers ~= h[64] + 64 accum
// + temps ~= 145 VGPRs. R1 kept ti+tj+h (192+) live -> hit the 256-VGPR cap
// and spilled ~570 MB to scratch (the whole 1.4 ms).
__global__ __launch_bounds__(256, 1) void pnet_kernel(
    const float* __restrict__ x,
    const float* __restrict__ W1,  const float* __restrict__ b1,
    const float* __restrict__ g1,  const float* __restrict__ beta1,
    const float* __restrict__ We1, const float* __restrict__ be1,
    const float* __restrict__ ge1, const float* __restrict__ bte1,
    const float* __restrict__ We2, const float* __restrict__ be2,
    const float* __restrict__ ge2, const float* __restrict__ bte2,
    const float* __restrict__ Wg1, const float* __restrict__ bg1,
    const float* __restrict__ Wg2, const float* __restrict__ bg2,
    float* __restrict__ out)
{
    __shared__ float R[NN * 33];     // 33.8 KB staging for column reductions
    __shared__ float pA[8 * 32];
    __shared__ float pB[8 * 32];
    __shared__ float redmax[DD];
    __shared__ float redmin[DD];
    __shared__ float xg[2 * DD];
    __shared__ float hid[DD];

    const int b = blockIdx.x;
    const int t = threadIdx.x;          // node index
    const int dl = t & 31;              // reduction column within 32-wide pass
    const int gg = t >> 5;              // reduction row-group (0..7)

    // ---------------- layer 1: h = bn(relu(x @ W1 + b1)) ----------------
    float4 xv = *(const float4*)(x + ((size_t)b * NN + t) * 4);
    float h[DD];
#pragma unroll
    for (int i = 0; i < 16; ++i) {
        float4 a  = ((const float4*)b1)[i];
        float4 w0 = ((const float4*)W1)[0 * 16 + i];
        float4 w1 = ((const float4*)W1)[1 * 16 + i];
        float4 w2 = ((const float4*)W1)[2 * 16 + i];
        float4 w3 = ((const float4*)W1)[3 * 16 + i];
        a.x += xv.x * w0.x + xv.y * w1.x + xv.z * w2.x + xv.w * w3.x;
        a.y += xv.x * w0.y + xv.y * w1.y + xv.z * w2.y + xv.w * w3.y;
        a.z += xv.x * w0.z + xv.y * w1.z + xv.z * w2.z + xv.w * w3.z;
        a.w += xv.x * w0.w + xv.y * w1.w + xv.z * w2.w + xv.w * w3.w;
        float4 g  = ((const float4*)g1)[i];
        float4 bt = ((const float4*)beta1)[i];
        h[4 * i + 0] = g.x * fmaxf(a.x, 0.f) + bt.x;
        h[4 * i + 1] = g.y * fmaxf(a.y, 0.f) + bt.y;
        h[4 * i + 2] = g.z * fmaxf(a.z, 0.f) + bt.z;
        h[4 * i + 3] = g.w * fmaxf(a.w, 0.f) + bt.w;
    }

    // ---------------- two edge convs ----------------
    const float* Wes[2]  = {We1, We2};
    const float* bes[2]  = {be1, be2};
    const float* ges[2]  = {ge1, ge2};
    const float* btes[2] = {bte1, bte2};

    for (int c = 0; c < 2; ++c) {
        const float* We = Wes[c];

        // ---- pass A: tj = h @ Wj (weight rows 64..127) ----
        {
            float4 tj[16];
#pragma unroll
            for (int i = 0; i < 16; ++i) tj[i] = make_float4(0.f, 0.f, 0.f, 0.f);
#pragma unroll 4
            for (int k = 0; k < 64; ++k) {
                float hk = h[k];
                const float4* wj = (const float4*)(We + (64 + k) * 64);
#pragma unroll
                for (int i = 0; i < 16; ++i) {
                    float4 w = wj[i];
                    tj[i].x = fmaf(hk, w.x, tj[i].x);
                    tj[i].y = fmaf(hk, w.y, tj[i].y);
                    tj[i].z = fmaf(hk, w.z, tj[i].z);
                    tj[i].w = fmaf(hk, w.w, tj[i].w);
                }
            }

            // per-batch max/min of tj over nodes, two 32-column passes
#pragma unroll
            for (int p = 0; p < 2; ++p) {
                __syncthreads();
#pragma unroll
                for (int i = 0; i < 8; ++i) {
                    int ii = p * 8 + i;
                    R[t * 33 + 4 * i + 0] = tj[ii].x;
                    R[t * 33 + 4 * i + 1] = tj[ii].y;
                    R[t * 33 + 4 * i + 2] = tj[ii].z;
                    R[t * 33 + 4 * i + 3] = tj[ii].w;
                }
                __syncthreads();
                float mx = -3.402823466e+38f, mn = 3.402823466e+38f;
#pragma unroll
                for (int s = 0; s < 32; ++s) {
                    float v = R[(gg * 32 + s) * 33 + dl];
                    mx = fmaxf(mx, v);
                    mn = fminf(mn, v);
                }
                pA[gg * 32 + dl] = mx;
                pB[gg * 32 + dl] = mn;
                __syncthreads();
                if (t < 32) {
                    float amax = pA[t], amin = pB[t];
#pragma unroll
                    for (int q = 1; q < 8; ++q) {
                        amax = fmaxf(amax, pA[q * 32 + t]);
                        amin = fminf(amin, pB[q * 32 + t]);
                    }
                    redmax[p * 32 + t] = amax;
                    redmin[p * 32 + t] = amin;
                }
            }
            __syncthreads();
        } // tj registers die here

        // ---- pass B: ti = h @ Wi (weight rows 0..63), then epilogue ----
        {
            float4 ti[16];
#pragma unroll
            for (int i = 0; i < 16; ++i) ti[i] = make_float4(0.f, 0.f, 0.f, 0.f);
#pragma unroll 4
            for (int k = 0; k < 64; ++k) {
                float hk = h[k];
                const float4* wi = (const float4*)(We + k * 64);
#pragma unroll
                for (int i = 0; i < 16; ++i) {
                    float4 w = wi[i];
                    ti[i].x = fmaf(hk, w.x, ti[i].x);
                    ti[i].y = fmaf(hk, w.y, ti[i].y);
                    ti[i].z = fmaf(hk, w.z, ti[i].z);
                    ti[i].w = fmaf(hk, w.w, ti[i].w);
                }
            }

            // h_new[d] = ge[d]*relu(ti[d] + pick(tj red) + be[d]) + bte[d]
            // (monotonicity: ge>=0 -> max_m tj, ge<0 -> min_m tj)
            const float4* gev  = (const float4*)ges[c];
            const float4* bev  = (const float4*)bes[c];
            const float4* btev = (const float4*)btes[c];
#pragma unroll
            for (int i = 0; i < 16; ++i) {
                float4 gv  = gev[i];
                float4 be4 = bev[i];
                float4 bt4 = btev[i];
                float s0 = ti[i].x + (gv.x >= 0.f ? redmax[4 * i + 0] : redmin[4 * i + 0]) + be4.x;
                float s1 = ti[i].y + (gv.y >= 0.f ? redmax[4 * i + 1] : redmin[4 * i + 1]) + be4.y;
                float s2 = ti[i].z + (gv.z >= 0.f ? redmax[4 * i + 2] : redmin[4 * i + 2]) + be4.z;
                float s3 = ti[i].w + (gv.w >= 0.f ? redmax[4 * i + 3] : redmin[4 * i + 3]) + be4.w;
                h[4 * i + 0] = gv.x * fmaxf(s0, 0.f) + bt4.x;
                h[4 * i + 1] = gv.y * fmaxf(s1, 0.f) + bt4.y;
                h[4 * i + 2] = gv.z * fmaxf(s2, 0.f) + bt4.z;
                h[4 * i + 3] = gv.w * fmaxf(s3, 0.f) + bt4.w;
            }
            __syncthreads();   // redmax/redmin free before next layer reuses them
        }
    }

    // ---------------- global pooling: mean & max over nodes ----------------
#pragma unroll
    for (int p = 0; p < 2; ++p) {
        __syncthreads();
#pragma unroll
        for (int i = 0; i < 8; ++i) {
            R[t * 33 + 4 * i + 0] = h[p * 32 + 4 * i + 0];
            R[t * 33 + 4 * i + 1] = h[p * 32 + 4 * i + 1];
            R[t * 33 + 4 * i + 2] = h[p * 32 + 4 * i + 2];
            R[t * 33 + 4 * i + 3] = h[p * 32 + 4 * i + 3];
        }
        __syncthreads();
        float mx = -3.402823466e+38f, sm = 0.f;
#pragma unroll
        for (int s = 0; s < 32; ++s) {
            float v = R[(gg * 32 + s) * 33 + dl];
            mx = fmaxf(mx, v);
            sm += v;
        }
        pA[gg * 32 + dl] = mx;
        pB[gg * 32 + dl] = sm;
        __syncthreads();
        if (t < 32) {
            float amax = pA[t], asum = pB[t];
#pragma unroll
            for (int q = 1; q < 8; ++q) {
                amax = fmaxf(amax, pA[q * 32 + t]);
                asum += pB[q * 32 + t];
            }
            xg[p * 32 + t]      = asum * (1.f / 256.f);  // mean half
            xg[64 + p * 32 + t] = amax;                  // max half
        }
    }
    __syncthreads();

    // ---------------- head MLP ----------------
    if (t < 64) {
        float a = bg1[t];
#pragma unroll 8
        for (int k = 0; k < 128; ++k) a += xg[k] * Wg1[k * 64 + t];
        hid[t] = fmaxf(a, 0.f);
    }
    __syncthreads();
    if (t < 2) {
        float o = bg2[t];
#pragma unroll 8
        for (int j = 0; j < 64; ++j) o += hid[j] * Wg2[j * 2 + t];
        out[b * 2 + t] = o;
    }
}

extern "C" void kernel_launch(void* const* d_in, const int* in_sizes, int n_in,
                              void* d_out, int out_size, void* d_ws, size_t ws_size,
                              hipStream_t stream) {
    const float* x     = (const float*)d_in[0];
    const float* W1    = (const float*)d_in[1];
    const float* b1    = (const float*)d_in[2];
    const float* g1    = (const float*)d_in[3];
    const float* beta1 = (const float*)d_in[4];
    const float* We1   = (const float*)d_in[5];
    const float* be1   = (const float*)d_in[6];
    const float* ge1   = (const float*)d_in[7];
    const float* bte1  = (const float*)d_in[8];
    const float* We2   = (const float*)d_in[9];
    const float* be2   = (const float*)d_in[10];
    const float* ge2   = (const float*)d_in[11];
    const float* bte2  = (const float*)d_in[12];
    const float* Wg1   = (const float*)d_in[13];
    const float* bg1   = (const float*)d_in[14];
    const float* Wg2   = (const float*)d_in[15];
    const float* bg2   = (const float*)d_in[16];

    pnet_kernel<<<dim3(NB), dim3(NN), 0, stream>>>(
        x, W1, b1, g1, beta1, We1, be1, ge1, bte1,
        We2, be2, ge2, bte2, Wg1, bg1, Wg2, bg2, (float*)d_out);
}

// Round 3
// 244.353 us; speedup vs baseline: 5.7927x; 1.7522x over previous
//
#include <hip/hip_runtime.h>

#define NB 32
#define NN 256
#define DD 64

// One block per batch (32 blocks), one thread per node (256 threads).
// R3: fully-unrolled k-loops (constant indexing -> arrays stay in VGPRs;
// R2's "#pragma unroll 4" made h[k] dynamically indexed -> scratch, 350us of
// L2-latency round trips at VGPR_Count=56). Two-pass structure retained so
// only one 64-float accumulator set is live at a time (R1 kept two -> 256
// VGPR cap -> 570MB of HBM spill traffic). Layer loop replaced by a lambda
// called twice with explicit pointers (no dynamically-indexed pointer array).
__global__ __launch_bounds__(256, 1) void pnet_kernel(
    const float* __restrict__ x,
    const float* __restrict__ W1,  const float* __restrict__ b1,
    const float* __restrict__ g1,  const float* __restrict__ beta1,
    const float* __restrict__ We1, const float* __restrict__ be1,
    const float* __restrict__ ge1, const float* __restrict__ bte1,
    const float* __restrict__ We2, const float* __restrict__ be2,
    const float* __restrict__ ge2, const float* __restrict__ bte2,
    const float* __restrict__ Wg1, const float* __restrict__ bg1,
    const float* __restrict__ Wg2, const float* __restrict__ bg2,
    float* __restrict__ out)
{
    __shared__ float R[NN * 33];     // 33.8 KB staging for column reductions
    __shared__ float pA[8 * 32];
    __shared__ float pB[8 * 32];
    __shared__ float redmax[DD];
    __shared__ float redmin[DD];
    __shared__ float xg[2 * DD];
    __shared__ float hid[DD];

    const int b = blockIdx.x;
    const int t = threadIdx.x;          // node index
    const int dl = t & 31;              // reduction column within 32-wide pass
    const int gg = t >> 5;              // reduction row-group (0..7)

    // ---------------- layer 1: h = bn(relu(x @ W1 + b1)) ----------------
    float4 xv = *(const float4*)(x + ((size_t)b * NN + t) * 4);
    float h[DD];
#pragma unroll
    for (int i = 0; i < 16; ++i) {
        float4 a  = ((const float4*)b1)[i];
        float4 w0 = ((const float4*)W1)[0 * 16 + i];
        float4 w1 = ((const float4*)W1)[1 * 16 + i];
        float4 w2 = ((const float4*)W1)[2 * 16 + i];
        float4 w3 = ((const float4*)W1)[3 * 16 + i];
        a.x += xv.x * w0.x + xv.y * w1.x + xv.z * w2.x + xv.w * w3.x;
        a.y += xv.x * w0.y + xv.y * w1.y + xv.z * w2.y + xv.w * w3.y;
        a.z += xv.x * w0.z + xv.y * w1.z + xv.z * w2.z + xv.w * w3.z;
        a.w += xv.x * w0.w + xv.y * w1.w + xv.z * w2.w + xv.w * w3.w;
        float4 g  = ((const float4*)g1)[i];
        float4 bt = ((const float4*)beta1)[i];
        h[4 * i + 0] = g.x * fmaxf(a.x, 0.f) + bt.x;
        h[4 * i + 1] = g.y * fmaxf(a.y, 0.f) + bt.y;
        h[4 * i + 2] = g.z * fmaxf(a.z, 0.f) + bt.z;
        h[4 * i + 3] = g.w * fmaxf(a.w, 0.f) + bt.w;
    }

    // ---------------- edge conv (called twice) ----------------
    auto edge_conv = [&](const float* __restrict__ We, const float* __restrict__ be,
                         const float* __restrict__ ge, const float* __restrict__ bte) {
        // ---- pass A: tj = h @ Wj (weight rows 64..127); fully unrolled ----
        {
            float tj[DD];
#pragma unroll
            for (int i = 0; i < DD; ++i) tj[i] = 0.f;
#pragma unroll
            for (int k = 0; k < DD; ++k) {
                const float hk = h[k];
                const float4* wj = (const float4*)(We + (DD + k) * DD);
#pragma unroll
                for (int i = 0; i < 16; ++i) {
                    float4 w = wj[i];
                    tj[4 * i + 0] = fmaf(hk, w.x, tj[4 * i + 0]);
                    tj[4 * i + 1] = fmaf(hk, w.y, tj[4 * i + 1]);
                    tj[4 * i + 2] = fmaf(hk, w.z, tj[4 * i + 2]);
                    tj[4 * i + 3] = fmaf(hk, w.w, tj[4 * i + 3]);
                }
            }

            // per-batch max/min of tj over nodes, two 32-column passes
#pragma unroll
            for (int p = 0; p < 2; ++p) {
                __syncthreads();
#pragma unroll
                for (int i = 0; i < 32; ++i)
                    R[t * 33 + i] = tj[p * 32 + i];
                __syncthreads();
                float mx = -3.402823466e+38f, mn = 3.402823466e+38f;
#pragma unroll
                for (int s = 0; s < 32; ++s) {
                    float v = R[(gg * 32 + s) * 33 + dl];
                    mx = fmaxf(mx, v);
                    mn = fminf(mn, v);
                }
                pA[gg * 32 + dl] = mx;
                pB[gg * 32 + dl] = mn;
                __syncthreads();
                if (t < 32) {
                    float amax = pA[t], amin = pB[t];
#pragma unroll
                    for (int q = 1; q < 8; ++q) {
                        amax = fmaxf(amax, pA[q * 32 + t]);
                        amin = fminf(amin, pB[q * 32 + t]);
                    }
                    redmax[p * 32 + t] = amax;
                    redmin[p * 32 + t] = amin;
                }
            }
            __syncthreads();   // redmax/redmin visible to all
        } // tj registers die here

        // ---- pass B: ti = h @ Wi (weight rows 0..63), then epilogue ----
        {
            float ti[DD];
#pragma unroll
            for (int i = 0; i < DD; ++i) ti[i] = 0.f;
#pragma unroll
            for (int k = 0; k < DD; ++k) {
                const float hk = h[k];
                const float4* wi = (const float4*)(We + k * DD);
#pragma unroll
                for (int i = 0; i < 16; ++i) {
                    float4 w = wi[i];
                    ti[4 * i + 0] = fmaf(hk, w.x, ti[4 * i + 0]);
                    ti[4 * i + 1] = fmaf(hk, w.y, ti[4 * i + 1]);
                    ti[4 * i + 2] = fmaf(hk, w.z, ti[4 * i + 2]);
                    ti[4 * i + 3] = fmaf(hk, w.w, ti[4 * i + 3]);
                }
            }

            // h_new[d] = ge[d]*relu(ti[d] + pick(tj red over m) + be[d]) + bte[d]
            // monotonicity: ge>=0 -> max_m tj, ge<0 -> min_m tj
#pragma unroll
            for (int i = 0; i < 16; ++i) {
                float4 gv  = ((const float4*)ge)[i];
                float4 be4 = ((const float4*)be)[i];
                float4 bt4 = ((const float4*)bte)[i];
                float s0 = ti[4 * i + 0] + (gv.x >= 0.f ? redmax[4 * i + 0] : redmin[4 * i + 0]) + be4.x;
                float s1 = ti[4 * i + 1] + (gv.y >= 0.f ? redmax[4 * i + 1] : redmin[4 * i + 1]) + be4.y;
                float s2 = ti[4 * i + 2] + (gv.z >= 0.f ? redmax[4 * i + 2] : redmin[4 * i + 2]) + be4.z;
                float s3 = ti[4 * i + 3] + (gv.w >= 0.f ? redmax[4 * i + 3] : redmin[4 * i + 3]) + be4.w;
                h[4 * i + 0] = gv.x * fmaxf(s0, 0.f) + bt4.x;
                h[4 * i + 1] = gv.y * fmaxf(s1, 0.f) + bt4.y;
                h[4 * i + 2] = gv.z * fmaxf(s2, 0.f) + bt4.z;
                h[4 * i + 3] = gv.w * fmaxf(s3, 0.f) + bt4.w;
            }
            __syncthreads();   // h epilogue done before LDS reuse next layer
        }
    };

    edge_conv(We1, be1, ge1, bte1);
    edge_conv(We2, be2, ge2, bte2);

    // ---------------- global pooling: mean & max over nodes ----------------
#pragma unroll
    for (int p = 0; p < 2; ++p) {
        __syncthreads();
#pragma unroll
        for (int i = 0; i < 32; ++i)
            R[t * 33 + i] = h[p * 32 + i];
        __syncthreads();
        float mx = -3.402823466e+38f, sm = 0.f;
#pragma unroll
        for (int s = 0; s < 32; ++s) {
            float v = R[(gg * 32 + s) * 33 + dl];
            mx = fmaxf(mx, v);
            sm += v;
        }
        pA[gg * 32 + dl] = mx;
        pB[gg * 32 + dl] = sm;
        __syncthreads();
        if (t < 32) {
            float amax = pA[t], asum = pB[t];
#pragma unroll
            for (int q = 1; q < 8; ++q) {
                amax = fmaxf(amax, pA[q * 32 + t]);
                asum += pB[q * 32 + t];
            }
            xg[p * 32 + t]      = asum * (1.f / 256.f);  // mean half
            xg[64 + p * 32 + t] = amax;                  // max half
        }
    }
    __syncthreads();

    // ---------------- head MLP ----------------
    if (t < 64) {
        float a = bg1[t];
#pragma unroll
        for (int k = 0; k < 128; ++k) a = fmaf(xg[k], Wg1[k * 64 + t], a);
        hid[t] = fmaxf(a, 0.f);
    }
    __syncthreads();
    if (t < 2) {
        float o = bg2[t];
#pragma unroll
        for (int j = 0; j < 64; ++j) o = fmaf(hid[j], Wg2[j * 2 + t], o);
        out[b * 2 + t] = o;
    }
}

extern "C" void kernel_launch(void* const* d_in, const int* in_sizes, int n_in,
                              void* d_out, int out_size, void* d_ws, size_t ws_size,
                              hipStream_t stream) {
    const float* x     = (const float*)d_in[0];
    const float* W1    = (const float*)d_in[1];
    const float* b1    = (const float*)d_in[2];
    const float* g1    = (const float*)d_in[3];
    const float* beta1 = (const float*)d_in[4];
    const float* We1   = (const float*)d_in[5];
    const float* be1   = (const float*)d_in[6];
    const float* ge1   = (const float*)d_in[7];
    const float* bte1  = (const float*)d_in[8];
    const float* We2   = (const float*)d_in[9];
    const float* be2   = (const float*)d_in[10];
    const float* ge2   = (const float*)d_in[11];
    const float* bte2  = (const float*)d_in[12];
    const float* Wg1   = (const float*)d_in[13];
    const float* bg1   = (const float*)d_in[14];
    const float* Wg2   = (const float*)d_in[15];
    const float* bg2   = (const float*)d_in[16];

    pnet_kernel<<<dim3(NB), dim3(NN), 0, stream>>>(
        x, W1, b1, g1, beta1, We1, be1, ge1, bte1,
        We2, be2, ge2, bte2, Wg1, bg1, Wg2, bg2, (float*)d_out);
}